// Round 6
// baseline (56.077 us; speedup 1.0000x reference)
//
#include <hip/hip_runtime.h>
#include <hip/hip_bf16.h>

#define KN 4096
#define CN 10
#define DN 128
#define BN 1000
#define LN 512
#define UB 4096   // unsup blocks: 128 i-chunks (32 rows) x 32 j-chunks (128 cols)

typedef float f32x4 __attribute__((ext_vector_type(4)));
typedef short bf16x8 __attribute__((ext_vector_type(8)));

__device__ __forceinline__ short bf16bits(float x) {
    __hip_bfloat16 h = __float2bfloat16(x);
    return *reinterpret_cast<short*>(&h);
}
// async global->LDS, 16B/lane, dest = wave-uniform base + lane*16
__device__ __forceinline__ void gload_lds16(const float* g, void* l) {
    __builtin_amdgcn_global_load_lds(
        (const __attribute__((address_space(1))) void*)g,
        (__attribute__((address_space(3))) void*)l, 16, 0, 0);
}

// ---------------- K1: prep (blocks 0..511) + P = embs @ W^T (blocks 512..575) --
__global__ __launch_bounds__(256) void w2v_prep(const float* __restrict__ embs,
                                                const float* __restrict__ W,
                                                float* __restrict__ sqn,
                                                short* __restrict__ ebf,
                                                float* __restrict__ P) {
    int blk = blockIdx.x, t = threadIdx.x;
    if (blk < 512) {
        int row = t >> 5, lane = t & 31;
        int r = blk * 8 + row;
        float4 v = ((const float4*)embs)[r * 32 + lane];
        short4 s4;
        s4.x = bf16bits(v.x); s4.y = bf16bits(v.y);
        s4.z = bf16bits(v.z); s4.w = bf16bits(v.w);
        ((short4*)ebf)[r * 32 + lane] = s4;
        float ss = v.x * v.x + v.y * v.y + v.z * v.z + v.w * v.w;
        #pragma unroll
        for (int m = 16; m >= 1; m >>= 1) ss += __shfl_xor(ss, m, 64);
        if (lane == 0) sqn[r] = ss;
        return;
    }
    int pb = blk - 512;
    int r = pb * 64 + (t >> 2);
    int q = t & 3;
    const float4* er = (const float4*)(embs + (size_t)r * DN) + q * 8;
    const float4* w4 = (const float4*)W;
    float s[CN];
    #pragma unroll
    for (int c = 0; c < CN; ++c) s[c] = 0.f;
    #pragma unroll
    for (int d4 = 0; d4 < 8; ++d4) {
        float4 e = er[d4];
        #pragma unroll
        for (int c = 0; c < CN; ++c) {
            float4 w = w4[c * 32 + q * 8 + d4];
            s[c] += e.x * w.x + e.y * w.y + e.z * w.z + e.w * w.w;
        }
    }
    #pragma unroll
    for (int c = 0; c < CN; ++c) {
        s[c] += __shfl_xor(s[c], 1, 64);
        s[c] += __shfl_xor(s[c], 2, 64);
    }
    if (q == 0) {
        float* pr = P + (size_t)r * 12;
        #pragma unroll
        for (int c = 0; c < CN; ++c) pr[c] = s[c];
        pr[10] = 0.f; pr[11] = 0.f;
    }
}

// ---------------- K2: unsup (blocks 0..4095, 1 wave each) + sup (4096..5095) ---
__global__ __launch_bounds__(64) void w2v_main(const short* __restrict__ ebf,
                                               const float* __restrict__ sqn,
                                               const float* __restrict__ pc,
                                               const float* __restrict__ P,
                                               const int* __restrict__ reads,
                                               const int* __restrict__ labels,
                                               float* __restrict__ psup,
                                               float* __restrict__ puns) {
    __shared__ char pcT[16 * 1040];   // 16 row-pairs x (1024B + 16B pad)
    int blk = blockIdx.x, t = threadIdx.x;

    if (blk < UB) {
        // ============ unsupervised 32x128 tile, one autonomous wave ============
        int i0 = (blk >> 5) * 32;
        int j0 = (blk & 31) * 128;
        int lr = t & 15, lg = t >> 4;

        const short* Arow = ebf + (size_t)(i0 + lr) * DN;
        const short* Brow = ebf + (size_t)(j0 + lr) * DN;

        f32x4 acc4[2][8];
        #pragma unroll
        for (int mi = 0; mi < 2; ++mi)
            #pragma unroll
            for (int nj = 0; nj < 8; ++nj)
                acc4[mi][nj] = (f32x4){0.f, 0.f, 0.f, 0.f};

        #pragma unroll
        for (int kk = 0; kk < 4; ++kk) {
            int ko = kk * 32 + lg * 8;
            bf16x8 a0 = *(const bf16x8*)(Arow + ko);
            bf16x8 a1 = *(const bf16x8*)(Arow + (size_t)16 * DN + ko);
            bf16x8 bfr[8];
            #pragma unroll
            for (int nj = 0; nj < 8; ++nj)
                bfr[nj] = *(const bf16x8*)(Brow + (size_t)nj * 16 * DN + ko);
            #pragma unroll
            for (int nj = 0; nj < 8; ++nj) {
                acc4[0][nj] = __builtin_amdgcn_mfma_f32_16x16x32_bf16(
                    a0, bfr[nj], acc4[0][nj], 0, 0, 0);
                acc4[1][nj] = __builtin_amdgcn_mfma_f32_16x16x32_bf16(
                    a1, bfr[nj], acc4[1][nj], 0, 0, 0);
            }
        }
        __builtin_amdgcn_sched_barrier(0);

        // sq gathers (issued before pc so their waits never drain pc)
        float siv[8], sjv[8];
        #pragma unroll
        for (int mi = 0; mi < 2; ++mi)
            #pragma unroll
            for (int v = 0; v < 4; ++v)
                siv[mi * 4 + v] = sqn[i0 + mi * 16 + lg * 4 + v];
        #pragma unroll
        for (int nj = 0; nj < 8; ++nj) sjv[nj] = sqn[j0 + nj * 16 + lr];
        __builtin_amdgcn_sched_barrier(0);

        // pc tile -> LDS, 16 async 1KB DMAs (pairs of rows), issued LAST in FIFO
        int rsub = t >> 5, csub = t & 31;
        #pragma unroll
        for (int p = 0; p < 16; ++p) {
            const float* src = pc + (size_t)(i0 + 2 * p + rsub) * KN + j0 + csub * 4;
            gload_lds16(src, pcT + p * 1040);
        }
        __builtin_amdgcn_sched_barrier(0);

        // epilogue: mi=0 needs pairs 0-7 (vmcnt<=8), mi=1 needs all (vmcnt 0)
        float part = 0.f;
        #pragma unroll
        for (int mi = 0; mi < 2; ++mi) {
            if (mi == 0) { asm volatile("s_waitcnt vmcnt(8)" ::: "memory"); }
            else         { asm volatile("s_waitcnt vmcnt(0)" ::: "memory"); }
            __builtin_amdgcn_sched_barrier(0);
            #pragma unroll
            for (int v = 0; v < 4; ++v) {
                int row = mi * 16 + lg * 4 + v;
                const float* prow =
                    (const float*)(pcT + (row >> 1) * 1040 + (row & 1) * 512);
                float si = siv[mi * 4 + v];
                #pragma unroll
                for (int nj = 0; nj < 8; ++nj) {
                    float pp = prow[nj * 16 + lr];
                    float sq = fmaxf(si + sjv[nj] - 2.f * acc4[mi][nj][v], 0.f);
                    float dd = sqrtf(sq);
                    float tt = fmaf(pp, dd, __expf(-dd));
                    part += (pp != 0.f) ? tt : 0.f;
                }
            }
        }
        #pragma unroll
        for (int off = 32; off > 0; off >>= 1) part += __shfl_down(part, off, 64);
        if (t == 0) puns[blk] = part;
        return;
    }

    // ============ supervised via P-gather, one wave per read ============
    int b = blk - UB;
    const int4* rr = (const int4*)(reads + (size_t)b * LN);
    int4 r0 = rr[t * 2], r1 = rr[t * 2 + 1];
    int idx[8] = { r0.x, r0.y, r0.z, r0.w, r1.x, r1.y, r1.z, r1.w };
    const float4* P4 = (const float4*)P;
    float s[12];
    #pragma unroll
    for (int i = 0; i < 12; ++i) s[i] = 0.f;
    #pragma unroll
    for (int k = 0; k < 8; ++k) {
        size_t o = (size_t)idx[k] * 3;
        float4 x = P4[o], y = P4[o + 1], z = P4[o + 2];
        s[0] += x.x; s[1] += x.y; s[2]  += x.z; s[3]  += x.w;
        s[4] += y.x; s[5] += y.y; s[6]  += y.z; s[7]  += y.w;
        s[8] += z.x; s[9] += z.y; s[10] += z.z; s[11] += z.w;
    }
    #pragma unroll
    for (int off = 32; off > 0; off >>= 1)
        #pragma unroll
        for (int i = 0; i < CN; ++i) s[i] += __shfl_down(s[i], off, 64);
    if (t == 0) {
        float m = s[0];
        #pragma unroll
        for (int c = 1; c < CN; ++c) m = fmaxf(m, s[c]);
        float se = 0.f;
        #pragma unroll
        for (int c = 0; c < CN; ++c) se += __expf(s[c] - m);
        float lse = m + __logf(se);
        psup[b] = -(s[labels[b]] - lse);
    }
}

// ---------------- K3: final reduce + combine -----------------------------------
__global__ __launch_bounds__(256) void w2v_final(const float* __restrict__ psup,
                                                 const float* __restrict__ puns,
                                                 const float* __restrict__ delta,
                                                 float* __restrict__ out) {
    __shared__ float r1[4], r2[4];
    int t = threadIdx.x;
    float a = 0.f, bsum = 0.f;
    for (int i = t; i < BN; i += 256)   a += psup[i];
    for (int i = t; i < UB; i += 256)   bsum += puns[i];
    #pragma unroll
    for (int off = 32; off > 0; off >>= 1) {
        a += __shfl_down(a, off, 64);
        bsum += __shfl_down(bsum, off, 64);
    }
    int lane = t & 63, wave = t >> 6;
    if (lane == 0) { r1[wave] = a; r2[wave] = bsum; }
    __syncthreads();
    if (t == 0) {
        float sup = (r1[0] + r1[1]) + (r1[2] + r1[3]);
        float uns = ((r2[0] + r2[1]) + (r2[2] + r2[3])) * (1.f / 16777216.f);
        float d = delta[0];
        out[0] = d * sup + (1.f - d) * uns;
    }
}

extern "C" void kernel_launch(void* const* d_in, const int* in_sizes, int n_in,
                              void* d_out, int out_size, void* d_ws, size_t ws_size,
                              hipStream_t stream) {
    const float* pc     = (const float*)d_in[0];
    const int*   reads  = (const int*)  d_in[1];
    const int*   labels = (const int*)  d_in[2];
    const float* delta  = (const float*)d_in[3];
    const float* embs   = (const float*)d_in[4];
    const float* W      = (const float*)d_in[5];
    float* out = (float*)d_out;

    char* ws = (char*)d_ws;
    float* sqn  = (float*)ws;                 // 4096 f32
    float* P    = (float*)(ws + 16384);       // 4096x12 f32
    short* ebf  = (short*)(ws + 212992);      // 4096x128 bf16 (1 MB)
    float* psup = (float*)(ws + 1261568);     // 1000 f32
    float* puns = (float*)(ws + 1265664);     // 4096 f32

    w2v_prep<<<576, 256, 0, stream>>>(embs, W, sqn, ebf, P);
    w2v_main<<<UB + BN, 64, 0, stream>>>(ebf, sqn, pc, P, reads, labels, psup, puns);
    w2v_final<<<1, 256, 0, stream>>>(psup, puns, delta, out);
}